// Round 3
// baseline (109.216 us; speedup 1.0000x reference)
//
#include <hip/hip_runtime.h>

#define GFINE 128
#define GC 64
#define NCELLS (GC * GC * GC)   // 262144
#define CIN 32
#define COUT 64
#define CPW 32                  // cells (output rows) per wave

// ---- Kernel A: scatter input rows into dense fine-grid + coarse occupancy flags ----
__global__ void scatter_kernel(const int* __restrict__ pos, int n,
                               int* __restrict__ idx_grid, int* __restrict__ flags) {
    int i = blockIdx.x * blockDim.x + threadIdx.x;
    if (i >= n) return;
    int x = pos[i * 3 + 0];
    int y = pos[i * 3 + 1];
    int z = pos[i * 3 + 2];
    idx_grid[(x * GFINE + y) * GFINE + z] = i;
    flags[((x >> 1) * GC + (y >> 1)) * GC + (z >> 1)] = 1;   // benign race
}

// ---- Kernel B1: per-1024-cell block exclusive scan of flags; emit block sums ----
__global__ void scan1_kernel(const int* __restrict__ flags, int* __restrict__ scan,
                             int* __restrict__ blockSums) {
    __shared__ int lds[256];
    int tid = threadIdx.x, bid = blockIdx.x;
    int4 v = ((const int4*)flags)[bid * 256 + tid];
    int s = v.x + v.y + v.z + v.w;
    lds[tid] = s;
    __syncthreads();
    for (int off = 1; off < 256; off <<= 1) {
        int t = (tid >= off) ? lds[tid - off] : 0;
        __syncthreads();
        lds[tid] += t;
        __syncthreads();
    }
    int incl = lds[tid];
    int excl = incl - s;
    int4 o;
    o.x = excl;
    o.y = excl + v.x;
    o.z = excl + v.x + v.y;
    o.w = excl + v.x + v.y + v.z;
    ((int4*)scan)[bid * 256 + tid] = o;
    if (tid == 255) blockSums[bid] = incl;
}

// ---- Kernel B2: exclusive scan of the 256 block sums ----
__global__ void scan2_kernel(int* __restrict__ blockSums) {
    __shared__ int lds[256];
    int tid = threadIdx.x;
    int s = blockSums[tid];
    lds[tid] = s;
    __syncthreads();
    for (int off = 1; off < 256; off <<= 1) {
        int t = (tid >= off) ? lds[tid - off] : 0;
        __syncthreads();
        lds[tid] += t;
        __syncthreads();
    }
    blockSums[tid] = lds[tid] - s;   // exclusive
}

// ---- Kernel B3: compact occupied cells into rank-ordered list; write out_pos ----
__global__ void compact_kernel(const int* __restrict__ flags, const int* __restrict__ scan,
                               const int* __restrict__ blockSums,
                               int* __restrict__ cellList, float* __restrict__ out_pos) {
    int cell = blockIdx.x * blockDim.x + threadIdx.x;
    if (cell >= NCELLS) return;
    if (!flags[cell]) return;
    int m = scan[cell] + blockSums[cell >> 10];
    cellList[m] = cell;
    int cx = cell >> 12, cy = (cell >> 6) & 63, cz = cell & 63;
    out_pos[m * 3 + 0] = cx + 0.25f;
    out_pos[m * 3 + 1] = cy + 0.25f;
    out_pos[m * 3 + 2] = cz + 0.25f;
}

// Load one feature row (32 floats) into an 8x float4 register buffer.
#define LOADF(BUF, R)                                                      \
    {                                                                      \
        const float4* _f4 = (const float4*)(feat + (size_t)(R) * CIN);     \
        _Pragma("unroll") for (int q = 0; q < 8; ++q) (BUF)[q] = _f4[q];   \
    }

// acc LDS row J += dot(BUF, wreg) for this lane's output channel.
#define DOFMA(BUF, J)                                                      \
    {                                                                      \
        float _s0 = 0.f, _s1 = 0.f, _s2 = 0.f, _s3 = 0.f;                  \
        _Pragma("unroll") for (int q = 0; q < 8; ++q) {                    \
            float4 _a = (BUF)[q];                                          \
            _s0 = fmaf(_a.x, wreg[4 * q + 0], _s0);                        \
            _s1 = fmaf(_a.y, wreg[4 * q + 1], _s1);                        \
            _s2 = fmaf(_a.z, wreg[4 * q + 2], _s2);                        \
            _s3 = fmaf(_a.w, wreg[4 * q + 3], _s3);                        \
        }                                                                  \
        la[(J) * COUT + lane] += (_s0 + _s1) + (_s2 + _s3);                \
    }

// ---- Kernel C: one wave per block, 32 cells per wave, lane = output channel.
// Software-pipelined hit loop: hit B's feature row loads while hit A FMAs.
__global__ __launch_bounds__(64, 4) void conv3_kernel(
    const float* __restrict__ feat, const float* __restrict__ weight,
    const int* __restrict__ idx_grid, const int* __restrict__ cellList,
    int M, float* __restrict__ out_feat) {
    __shared__ float la[CPW * COUT];   // 8 KB per wave
    const int lane = threadIdx.x;      // 0..63
    const int base = blockIdx.x * CPW; // grid sized so base < M
    int nj = M - base;
    if (nj > CPW) nj = CPW;

#pragma unroll
    for (int j = 0; j < CPW; ++j) la[j * COUT + lane] = 0.f;

    // lane l covers cell-slot (l&31); both wave halves duplicate the cell load
    const int l31 = lane & 31;
    int rank = base + l31;
    int cell = (rank < M) ? cellList[rank] : 0;   // clamped ranks masked by `valid`
    int cx = cell >> 12, cy = (cell >> 6) & 63, cz = cell & 63;
    int vfb = ((cx * 2) * GFINE + cy * 2) * GFINE + cz * 2;

    // gather all 32x8 tap indices: load L covers taps 2L (lanes 0-31), 2L+1 (32-63)
    int vr[4];
    unsigned maskk[8];
    const int hi = lane >> 5;
#pragma unroll
    for (int L = 0; L < 4; ++L) {
        int k = 2 * L + hi;
        int off = (k >> 2) * (GFINE * GFINE) + (((k >> 1) & 1) * GFINE) + (k & 1);
        vr[L] = idx_grid[vfb + off];
        unsigned long long b = __ballot(vr[L] >= 0);
        maskk[2 * L]     = (unsigned)(b & 0xffffffffull);
        maskk[2 * L + 1] = (unsigned)(b >> 32);
    }
    const unsigned valid = (nj >= 32) ? 0xffffffffu : ((1u << nj) - 1u);

#pragma unroll
    for (int k = 0; k < 8; ++k) {
        unsigned mk = maskk[k] & valid;
        if (mk == 0) continue;
        // tap-k weights resident in VGPRs, amortized over up to 32 cells
        float wreg[CIN];
#pragma unroll
        for (int c = 0; c < CIN; ++c) wreg[c] = weight[(k * CIN + c) * COUT + lane];

        float4 bufA[8], bufB[8];
        int jA = (int)__builtin_ctz(mk); mk &= mk - 1;
        int rA = __builtin_amdgcn_readlane(vr[k >> 1], jA + (k & 1) * 32);
        LOADF(bufA, rA)
        bool tailA = true;
        while (mk) {
            int jB = (int)__builtin_ctz(mk); mk &= mk - 1;
            int rB = __builtin_amdgcn_readlane(vr[k >> 1], jB + (k & 1) * 32);
            LOADF(bufB, rB)
            DOFMA(bufA, jA)
            if (!mk) { DOFMA(bufB, jB) tailA = false; break; }
            jA = (int)__builtin_ctz(mk); mk &= mk - 1;
            rA = __builtin_amdgcn_readlane(vr[k >> 1], jA + (k & 1) * 32);
            LOADF(bufA, rA)
            DOFMA(bufB, jB)
        }
        if (tailA) DOFMA(bufA, jA)
    }

#pragma unroll
    for (int j = 0; j < CPW; ++j)
        if (j < nj)
            out_feat[(size_t)(base + j) * COUT + lane] = la[j * COUT + lane];
}

extern "C" void kernel_launch(void* const* d_in, const int* in_sizes, int n_in,
                              void* d_out, int out_size, void* d_ws, size_t ws_size,
                              hipStream_t stream) {
    const float* feat   = (const float*)d_in[0];
    const int*   pos    = (const int*)d_in[1];
    const float* weight = (const float*)d_in[2];
    int n = in_sizes[1] / 3;
    int M = out_size / 67;   // out_feat M*64 + out_pos M*3

    char* ws = (char*)d_ws;
    int* idx_grid  = (int*)(ws);                                   // 8 MB
    int* flags     = (int*)(ws + (size_t)8388608);                 // 1 MB
    int* scan      = (int*)(ws + (size_t)8388608 + 1048576);       // 1 MB
    int* blockSums = (int*)(ws + (size_t)8388608 + 2097152);       // 256 ints
    int* cellList  = (int*)(ws + (size_t)8388608 + 2097152 + 4096);// 1 MB

    hipMemsetAsync(idx_grid, 0xFF, (size_t)GFINE * GFINE * GFINE * 4, stream); // -1
    hipMemsetAsync(flags, 0, (size_t)NCELLS * 4, stream);

    scatter_kernel<<<(n + 255) / 256, 256, 0, stream>>>(pos, n, idx_grid, flags);
    scan1_kernel<<<256, 256, 0, stream>>>(flags, scan, blockSums);
    scan2_kernel<<<1, 256, 0, stream>>>(blockSums);

    float* out_feat = (float*)d_out;
    float* out_pos  = (float*)d_out + (size_t)M * COUT;
    compact_kernel<<<NCELLS / 256, 256, 0, stream>>>(flags, scan, blockSums,
                                                     cellList, out_pos);

    conv3_kernel<<<(M + CPW - 1) / CPW, 64, 0, stream>>>(feat, weight, idx_grid,
                                                         cellList, M, out_feat);
}

// Round 4
// 57.693 us; speedup vs baseline: 1.8931x; 1.8931x over previous
//
#include <hip/hip_runtime.h>

#define GFINE 128
#define GC 64
#define NCELLS (GC * GC * GC)   // 262144
#define CIN 32
#define COUT 64

typedef __attribute__((ext_vector_type(8))) short bf16x8;   // 8 bf16 (4 VGPR)
typedef __attribute__((ext_vector_type(4))) float f32x4;    // MFMA acc

// round-to-nearest-even float -> bf16 bits
__device__ __forceinline__ short f2bf(float f) {
    union { float f; unsigned u; } v; v.f = f;
    unsigned r = v.u + 0x7fffu + ((v.u >> 16) & 1u);
    return (short)(r >> 16);
}

// ---- Kernel A: scatter input rows into dense fine-grid + coarse occupancy flags ----
__global__ void scatter_kernel(const int* __restrict__ pos, int n,
                               int* __restrict__ idx_grid, int* __restrict__ flags) {
    int i = blockIdx.x * blockDim.x + threadIdx.x;
    if (i >= n) return;
    int x = pos[i * 3 + 0];
    int y = pos[i * 3 + 1];
    int z = pos[i * 3 + 2];
    idx_grid[(x * GFINE + y) * GFINE + z] = i;
    flags[((x >> 1) * GC + (y >> 1)) * GC + (z >> 1)] = 1;   // benign race
}

// ---- Kernel B1: per-1024-cell block exclusive scan of flags; emit block sums ----
__global__ void scan1_kernel(const int* __restrict__ flags, int* __restrict__ scan,
                             int* __restrict__ blockSums) {
    __shared__ int lds[256];
    int tid = threadIdx.x, bid = blockIdx.x;
    int4 v = ((const int4*)flags)[bid * 256 + tid];
    int s = v.x + v.y + v.z + v.w;
    lds[tid] = s;
    __syncthreads();
    for (int off = 1; off < 256; off <<= 1) {
        int t = (tid >= off) ? lds[tid - off] : 0;
        __syncthreads();
        lds[tid] += t;
        __syncthreads();
    }
    int incl = lds[tid];
    int excl = incl - s;
    int4 o;
    o.x = excl;
    o.y = excl + v.x;
    o.z = excl + v.x + v.y;
    o.w = excl + v.x + v.y + v.z;
    ((int4*)scan)[bid * 256 + tid] = o;
    if (tid == 255) blockSums[bid] = incl;
}

// ---- Kernel B2: exclusive scan of the 256 block sums ----
__global__ void scan2_kernel(int* __restrict__ blockSums) {
    __shared__ int lds[256];
    int tid = threadIdx.x;
    int s = blockSums[tid];
    lds[tid] = s;
    __syncthreads();
    for (int off = 1; off < 256; off <<= 1) {
        int t = (tid >= off) ? lds[tid - off] : 0;
        __syncthreads();
        lds[tid] += t;
        __syncthreads();
    }
    blockSums[tid] = lds[tid] - s;   // exclusive
}

// ---- Kernel B3: compact occupied cells into rank-ordered list; write out_pos ----
__global__ void compact_kernel(const int* __restrict__ flags, const int* __restrict__ scan,
                               const int* __restrict__ blockSums,
                               int* __restrict__ cellList, float* __restrict__ out_pos) {
    int cell = blockIdx.x * blockDim.x + threadIdx.x;
    if (cell >= NCELLS) return;
    if (!flags[cell]) return;
    int m = scan[cell] + blockSums[cell >> 10];
    cellList[m] = cell;
    int cx = cell >> 12, cy = (cell >> 6) & 63, cz = cell & 63;
    out_pos[m * 3 + 0] = cx + 0.25f;
    out_pos[m * 3 + 1] = cy + 0.25f;
    out_pos[m * 3 + 2] = cz + 0.25f;
}

// ---- Kernel W: pre-swizzle weights into MFMA B-fragment layout (bf16) ----
// wswz[(k*4+cb)*64 + lane] = bf16x8 { W[k][(lane>>4)*8+e][cb*16+(lane&15)] }
__global__ void wswz_kernel(const float* __restrict__ w, short* __restrict__ wswz) {
    int t = blockIdx.x * blockDim.x + threadIdx.x;   // 0..2047
    int lane = t & 63, cb = (t >> 6) & 3, k = t >> 8;
    bf16x8 o;
#pragma unroll
    for (int e = 0; e < 8; ++e)
        o[e] = f2bf(w[(k * CIN + ((lane >> 4) * 8 + e)) * COUT + cb * 16 + (lane & 15)]);
    ((bf16x8*)wswz)[t] = o;
}

// ---- Kernel C: MFMA gather-GEMM. One wave per 16 output cells.
// K=256 = 8 taps x 32 cin; A-frag rows = cells, gathered per-lane (32B chunks);
// B = pre-swizzled weights; 32x mfma_f32_16x16x32_bf16 per wave; no LDS.
__global__ __launch_bounds__(256) void conv6_kernel(
    const float* __restrict__ feat, const short* __restrict__ wswz,
    const int* __restrict__ idx_grid, const int* __restrict__ cellList,
    int M, float* __restrict__ out_feat) {
    const int lane = threadIdx.x & 63;
    const int wv = threadIdx.x >> 6;
    const int base = (blockIdx.x * 4 + wv) * 16;
    if (base >= M) return;
    const int cslot = lane & 15;     // A-frag row  = cell slot
    const int tgrp  = lane >> 4;     // A-frag K-chunk (8 elems) = cin chunk

    int rank = base + cslot;
    if (rank >= M) rank = M - 1;                 // dup last cell; C-write masked
    int cell = cellList[rank];
    int cx = cell >> 12, cy = (cell >> 6) & 63, cz = cell & 63;
    int vfb = ((cx * 2) * GFINE + cy * 2) * GFINE + cz * 2;

    // lane (cslot, tgrp) fetches tap indices tgrp and 4+tgrp of its cell
    int toff = ((tgrp >> 1) & 1) * GFINE + (tgrp & 1);
    int tA = idx_grid[vfb + toff];                       // taps 0..3
    int tB = idx_grid[vfb + GFINE * GFINE + toff];       // taps 4..7

    // Phase 1: gather all 8 taps' fp32 chunks (32B/lane), fully overlapped
    float4 u[8], v[8];
    int rr[8];
#pragma unroll
    for (int k = 0; k < 8; ++k) {
        int r = __shfl(k < 4 ? tA : tB, cslot + ((k & 3) << 4), 64);
        rr[k] = r;
        if (r >= 0) {
            const float4* fr = (const float4*)(feat + (size_t)r * CIN + tgrp * 8);
            u[k] = fr[0];
            v[k] = fr[1];
        }
    }

    // Phase 2: convert + 32 MFMAs (4 cout-blocks x 8 K-steps)
    const bf16x8* wf = (const bf16x8*)wswz;
    f32x4 acc0 = {0.f, 0.f, 0.f, 0.f}, acc1 = acc0, acc2 = acc0, acc3 = acc0;
#pragma unroll
    for (int k = 0; k < 8; ++k) {
        bf16x8 a = {0, 0, 0, 0, 0, 0, 0, 0};
        if (rr[k] >= 0) {
            a[0] = f2bf(u[k].x); a[1] = f2bf(u[k].y);
            a[2] = f2bf(u[k].z); a[3] = f2bf(u[k].w);
            a[4] = f2bf(v[k].x); a[5] = f2bf(v[k].y);
            a[6] = f2bf(v[k].z); a[7] = f2bf(v[k].w);
        }
        acc0 = __builtin_amdgcn_mfma_f32_16x16x32_bf16(a, wf[(k * 4 + 0) * 64 + lane], acc0, 0, 0, 0);
        acc1 = __builtin_amdgcn_mfma_f32_16x16x32_bf16(a, wf[(k * 4 + 1) * 64 + lane], acc1, 0, 0, 0);
        acc2 = __builtin_amdgcn_mfma_f32_16x16x32_bf16(a, wf[(k * 4 + 2) * 64 + lane], acc2, 0, 0, 0);
        acc3 = __builtin_amdgcn_mfma_f32_16x16x32_bf16(a, wf[(k * 4 + 3) * 64 + lane], acc3, 0, 0, 0);
    }

    // C-write: D row = tgrp*4+i (within tile), col = cslot (within cout-block)
#pragma unroll
    for (int i = 0; i < 4; ++i) {
        int row = base + tgrp * 4 + i;
        if (row < M) {
            float* o = out_feat + (size_t)row * COUT + cslot;
            o[0]  = acc0[i];
            o[16] = acc1[i];
            o[32] = acc2[i];
            o[48] = acc3[i];
        }
    }
}

extern "C" void kernel_launch(void* const* d_in, const int* in_sizes, int n_in,
                              void* d_out, int out_size, void* d_ws, size_t ws_size,
                              hipStream_t stream) {
    const float* feat   = (const float*)d_in[0];
    const int*   pos    = (const int*)d_in[1];
    const float* weight = (const float*)d_in[2];
    int n = in_sizes[1] / 3;
    int M = out_size / 67;   // out_feat M*64 + out_pos M*3

    char* ws = (char*)d_ws;
    int*   idx_grid  = (int*)(ws);                                       // 8 MB
    int*   flags     = (int*)(ws + (size_t)8388608);                     // 1 MB
    int*   scan      = (int*)(ws + (size_t)9437184);                     // 1 MB
    int*   blockSums = (int*)(ws + (size_t)10485760);                    // 4 KB
    int*   cellList  = (int*)(ws + (size_t)10489856);                    // 1 MB
    short* wswz      = (short*)(ws + (size_t)11538432);                  // 32 KB

    hipMemsetAsync(idx_grid, 0xFF, (size_t)GFINE * GFINE * GFINE * 4, stream); // -1
    hipMemsetAsync(flags, 0, (size_t)NCELLS * 4, stream);

    scatter_kernel<<<(n + 255) / 256, 256, 0, stream>>>(pos, n, idx_grid, flags);
    wswz_kernel<<<8, 256, 0, stream>>>(weight, wswz);
    scan1_kernel<<<256, 256, 0, stream>>>(flags, scan, blockSums);
    scan2_kernel<<<1, 256, 0, stream>>>(blockSums);

    float* out_feat = (float*)d_out;
    float* out_pos  = (float*)d_out + (size_t)M * COUT;
    compact_kernel<<<NCELLS / 256, 256, 0, stream>>>(flags, scan, blockSums,
                                                     cellList, out_pos);

    conv6_kernel<<<(M + 63) / 64, 256, 0, stream>>>(feat, wswz, idx_grid,
                                                    cellList, M, out_feat);
}

// Round 5
// 56.162 us; speedup vs baseline: 1.9447x; 1.0272x over previous
//
#include <hip/hip_runtime.h>

#define GFINE 128
#define GC 64
#define NCELLS (GC * GC * GC)   // 262144
#define CIN 32
#define COUT 64

typedef __attribute__((ext_vector_type(8))) short bf16x8;   // 8 bf16 (4 VGPR)
typedef __attribute__((ext_vector_type(4))) float f32x4;    // MFMA acc

// round-to-nearest-even float -> bf16 bits
__device__ __forceinline__ short f2bf(float f) {
    union { float f; unsigned u; } v; v.f = f;
    unsigned r = v.u + 0x7fffu + ((v.u >> 16) & 1u);
    return (short)(r >> 16);
}

// ---- Kernel F: fast fill of idx_grid (-1) and flags (0) in one pass ----
// Region: [0, 8 MB) = idx_grid -> -1 ; [8 MB, 9.25 MB) = flags -> 0.
// 589824 int4 stores total.
#define IDX_INT4 (GFINE * GFINE * GFINE / 4)          // 524288
#define FILL_INT4 (IDX_INT4 + NCELLS / 4)             // 589824
__global__ void fill_kernel(int4* __restrict__ p) {
    int i = blockIdx.x * blockDim.x + threadIdx.x;
    if (i >= FILL_INT4) return;
    int v = (i < IDX_INT4) ? -1 : 0;
    p[i] = make_int4(v, v, v, v);
}

// ---- Kernel A: scatter input rows into dense fine-grid + coarse occupancy flags ----
__global__ void scatter_kernel(const int* __restrict__ pos, int n,
                               int* __restrict__ idx_grid, int* __restrict__ flags) {
    int i = blockIdx.x * blockDim.x + threadIdx.x;
    if (i >= n) return;
    int x = pos[i * 3 + 0];
    int y = pos[i * 3 + 1];
    int z = pos[i * 3 + 2];
    idx_grid[(x * GFINE + y) * GFINE + z] = i;
    flags[((x >> 1) * GC + (y >> 1)) * GC + (z >> 1)] = 1;   // benign race
}

// ---- Kernel B1: per-1024-cell block exclusive scan of flags; emit block sums ----
__global__ void scan1_kernel(const int* __restrict__ flags, int* __restrict__ scan,
                             int* __restrict__ blockSums) {
    __shared__ int lds[256];
    int tid = threadIdx.x, bid = blockIdx.x;
    int4 v = ((const int4*)flags)[bid * 256 + tid];
    int s = v.x + v.y + v.z + v.w;
    lds[tid] = s;
    __syncthreads();
    for (int off = 1; off < 256; off <<= 1) {
        int t = (tid >= off) ? lds[tid - off] : 0;
        __syncthreads();
        lds[tid] += t;
        __syncthreads();
    }
    int incl = lds[tid];
    int excl = incl - s;
    int4 o;
    o.x = excl;
    o.y = excl + v.x;
    o.z = excl + v.x + v.y;
    o.w = excl + v.x + v.y + v.z;
    ((int4*)scan)[bid * 256 + tid] = o;
    if (tid == 255) blockSums[bid] = incl;
}

// ---- Kernel B2: exclusive scan of the 256 block sums ----
__global__ void scan2_kernel(int* __restrict__ blockSums) {
    __shared__ int lds[256];
    int tid = threadIdx.x;
    int s = blockSums[tid];
    lds[tid] = s;
    __syncthreads();
    for (int off = 1; off < 256; off <<= 1) {
        int t = (tid >= off) ? lds[tid - off] : 0;
        __syncthreads();
        lds[tid] += t;
        __syncthreads();
    }
    blockSums[tid] = lds[tid] - s;   // exclusive
}

// ---- Kernel B3: compact occupied cells into rank-ordered list; write out_pos ----
__global__ void compact_kernel(const int* __restrict__ flags, const int* __restrict__ scan,
                               const int* __restrict__ blockSums,
                               int* __restrict__ cellList, float* __restrict__ out_pos) {
    int cell = blockIdx.x * blockDim.x + threadIdx.x;
    if (cell >= NCELLS) return;
    if (!flags[cell]) return;
    int m = scan[cell] + blockSums[cell >> 10];
    cellList[m] = cell;
    int cx = cell >> 12, cy = (cell >> 6) & 63, cz = cell & 63;
    out_pos[m * 3 + 0] = cx + 0.25f;
    out_pos[m * 3 + 1] = cy + 0.25f;
    out_pos[m * 3 + 2] = cz + 0.25f;
}

// ---- Kernel W: pre-swizzle weights into MFMA B-fragment layout (bf16) ----
// wswz[(k*4+cb)*64 + lane] = bf16x8 { W[k][(lane>>4)*8+e][cb*16+(lane&15)] }
__global__ void wswz_kernel(const float* __restrict__ w, short* __restrict__ wswz) {
    int t = blockIdx.x * blockDim.x + threadIdx.x;   // 0..2047
    int lane = t & 63, cb = (t >> 6) & 3, k = t >> 8;
    bf16x8 o;
#pragma unroll
    for (int e = 0; e < 8; ++e)
        o[e] = f2bf(w[(k * CIN + ((lane >> 4) * 8 + e)) * COUT + cb * 16 + (lane & 15)]);
    ((bf16x8*)wswz)[t] = o;
}

// ---- Kernel C: MFMA gather-GEMM. One wave per 16 output cells.
// K=256 = 8 taps x 32 cin; A-frag rows = cells, gathered per-lane (32B chunks);
// B = pre-swizzled weights; 32x mfma_f32_16x16x32_bf16 per wave; no LDS.
__global__ __launch_bounds__(256) void conv6_kernel(
    const float* __restrict__ feat, const short* __restrict__ wswz,
    const int* __restrict__ idx_grid, const int* __restrict__ cellList,
    int M, float* __restrict__ out_feat) {
    const int lane = threadIdx.x & 63;
    const int wv = threadIdx.x >> 6;
    const int base = (blockIdx.x * 4 + wv) * 16;
    if (base >= M) return;
    const int cslot = lane & 15;     // A-frag row  = cell slot
    const int tgrp  = lane >> 4;     // A-frag K-chunk (8 elems) = cin chunk

    int rank = base + cslot;
    if (rank >= M) rank = M - 1;                 // dup last cell; C-write masked
    int cell = cellList[rank];
    int cx = cell >> 12, cy = (cell >> 6) & 63, cz = cell & 63;
    int vfb = ((cx * 2) * GFINE + cy * 2) * GFINE + cz * 2;

    // lane (cslot, tgrp) fetches tap indices tgrp and 4+tgrp of its cell
    int toff = ((tgrp >> 1) & 1) * GFINE + (tgrp & 1);
    int tA = idx_grid[vfb + toff];                       // taps 0..3
    int tB = idx_grid[vfb + GFINE * GFINE + toff];       // taps 4..7

    // Phase 1: gather all 8 taps' fp32 chunks (32B/lane), fully overlapped
    float4 u[8], v[8];
    int rr[8];
#pragma unroll
    for (int k = 0; k < 8; ++k) {
        int r = __shfl(k < 4 ? tA : tB, cslot + ((k & 3) << 4), 64);
        rr[k] = r;
        if (r >= 0) {
            const float4* fr = (const float4*)(feat + (size_t)r * CIN + tgrp * 8);
            u[k] = fr[0];
            v[k] = fr[1];
        }
    }

    // Phase 2: convert + 32 MFMAs (4 cout-blocks x 8 K-steps)
    const bf16x8* wf = (const bf16x8*)wswz;
    f32x4 acc0 = {0.f, 0.f, 0.f, 0.f}, acc1 = acc0, acc2 = acc0, acc3 = acc0;
#pragma unroll
    for (int k = 0; k < 8; ++k) {
        bf16x8 a = {0, 0, 0, 0, 0, 0, 0, 0};
        if (rr[k] >= 0) {
            a[0] = f2bf(u[k].x); a[1] = f2bf(u[k].y);
            a[2] = f2bf(u[k].z); a[3] = f2bf(u[k].w);
            a[4] = f2bf(v[k].x); a[5] = f2bf(v[k].y);
            a[6] = f2bf(v[k].z); a[7] = f2bf(v[k].w);
        }
        acc0 = __builtin_amdgcn_mfma_f32_16x16x32_bf16(a, wf[(k * 4 + 0) * 64 + lane], acc0, 0, 0, 0);
        acc1 = __builtin_amdgcn_mfma_f32_16x16x32_bf16(a, wf[(k * 4 + 1) * 64 + lane], acc1, 0, 0, 0);
        acc2 = __builtin_amdgcn_mfma_f32_16x16x32_bf16(a, wf[(k * 4 + 2) * 64 + lane], acc2, 0, 0, 0);
        acc3 = __builtin_amdgcn_mfma_f32_16x16x32_bf16(a, wf[(k * 4 + 3) * 64 + lane], acc3, 0, 0, 0);
    }

    // C-write: D row = tgrp*4+i (within tile), col = cslot (within cout-block)
#pragma unroll
    for (int i = 0; i < 4; ++i) {
        int row = base + tgrp * 4 + i;
        if (row < M) {
            float* o = out_feat + (size_t)row * COUT + cslot;
            o[0]  = acc0[i];
            o[16] = acc1[i];
            o[32] = acc2[i];
            o[48] = acc3[i];
        }
    }
}

extern "C" void kernel_launch(void* const* d_in, const int* in_sizes, int n_in,
                              void* d_out, int out_size, void* d_ws, size_t ws_size,
                              hipStream_t stream) {
    const float* feat   = (const float*)d_in[0];
    const int*   pos    = (const int*)d_in[1];
    const float* weight = (const float*)d_in[2];
    int n = in_sizes[1] / 3;
    int M = out_size / 67;   // out_feat M*64 + out_pos M*3

    char* ws = (char*)d_ws;
    int*   idx_grid  = (int*)(ws);                                       // 8 MB
    int*   flags     = (int*)(ws + (size_t)8388608);                     // 1 MB
    int*   scan      = (int*)(ws + (size_t)9437184);                     // 1 MB
    int*   blockSums = (int*)(ws + (size_t)10485760);                    // 4 KB
    int*   cellList  = (int*)(ws + (size_t)10489856);                    // 1 MB
    short* wswz      = (short*)(ws + (size_t)11538432);                  // 32 KB

    // custom fill: idx_grid = -1, flags = 0 (replaces 2x slow rocclr memset)
    fill_kernel<<<(FILL_INT4 + 255) / 256, 256, 0, stream>>>((int4*)ws);

    scatter_kernel<<<(n + 255) / 256, 256, 0, stream>>>(pos, n, idx_grid, flags);
    wswz_kernel<<<8, 256, 0, stream>>>(weight, wswz);
    scan1_kernel<<<256, 256, 0, stream>>>(flags, scan, blockSums);
    scan2_kernel<<<1, 256, 0, stream>>>(blockSums);

    float* out_feat = (float*)d_out;
    float* out_pos  = (float*)d_out + (size_t)M * COUT;
    compact_kernel<<<NCELLS / 256, 256, 0, stream>>>(flags, scan, blockSums,
                                                     cellList, out_pos);

    conv6_kernel<<<(M + 63) / 64, 256, 0, stream>>>(feat, wswz, idx_grid,
                                                    cellList, M, out_feat);
}